// Round 3
// baseline (883.717 us; speedup 1.0000x reference)
//
#include <hip/hip_runtime.h>

// Fused SIREN INR round 9. r8 base (TOK=128, 512 thr, 32x32x16 MFMA,
// fragment-ordered weights, chunk-major LDS, 2 barriers/layer) with
// MT=4 geometry: wave = 4 mt-tiles (128 feats) x 2 nt-tiles (64 tokens),
// waves paired on token halves. Halves LDS b-read traffic (the newly
// identified hidden bottleneck: r8 LDS read pipe = 384 cyc per 591-cyc
// k-step wall = 65%; now 32%) at the cost of 2x L2 a-traffic (43% of
// per-CU L2 link), covered by the 3-buffer rolling a-prefetch
// (issue->use = 2 k-steps ~590 cyc >> 225 cyc L2 hit).
// LEDGER:
//  - r7 token-split pipeline FAILED (+6%): re-attributed to 1-deep
//    a-prefetch (155-cyc window < L2 latency), NOT L2 bandwidth.
//  - r8 32x32x16 switch: MFMA busy flat 367us, VALU -46us, idle +39us
//    -> in-K-loop critical path is LDS reads, not the MFMA pipe.
//  - MFMA pipe floor (f16): 349 us. VALU (sines) ~177 us, serialized.

#define L_TOTAL 262144
#define TOK 128
#define THREADS 512
#define C_SC 4.77464829275686f  // 30/(2*pi)

typedef _Float16 f16x8 __attribute__((ext_vector_type(8)));
typedef _Float16 f16x4 __attribute__((ext_vector_type(4)));
typedef float    f32x4 __attribute__((ext_vector_type(4)));
typedef float    f32x16 __attribute__((ext_vector_type(16)));

#define N1 (512 * 256)                 // W_first elems
#define N2 (N1 + 5 * 512 * 512)        // + W_hidden
#define N3 (N2 + 16 * 512)             // + W_out padded to 16 rows
#define NBIAS 3072                     // 512 first + 5*512 hidden (pre-scaled)

// Fragment-ordered weights for 32x32x16 MFMA:
// dst[((rt*KS + ks)*64 + lane)*8 + e] = W[row = rt*32 + (lane&31)]
//                                        [col = ks*16 + (lane>>5)*8 + e]
// (one contiguous 1KB burst per (row-tile, ks) per wave)
__global__ void convert_weights(const float* __restrict__ Wf,
                                const float* __restrict__ Wh,
                                const float* __restrict__ Wo,
                                const float* __restrict__ bf,
                                const float* __restrict__ bh,
                                _Float16* __restrict__ o,
                                float* __restrict__ biasC) {
  int i = blockIdx.x * blockDim.x + threadIdx.x;
  if (i < N3) {
    float v;
    if (i < N1) {                      // first layer: 512x256, KS=16
      const int blk = i >> 9, w = i & 511;
      const int lane = w >> 3, e = w & 7;
      const int rt = blk >> 4, ks = blk & 15;
      const int row = rt * 32 + (lane & 31);
      const int col = ks * 16 + (lane >> 5) * 8 + e;
      v = Wf[row * 256 + col];
    } else if (i < N2) {               // hidden: 5 x 512x512, KS=32
      int j = i - N1;
      const int l = j >> 18;
      j &= (1 << 18) - 1;
      const int blk = j >> 9, w = j & 511;
      const int lane = w >> 3, e = w & 7;
      const int rt = blk >> 5, ks = blk & 31;
      const int row = rt * 32 + (lane & 31);
      const int col = ks * 16 + (lane >> 5) * 8 + e;
      v = Wh[l * (512 * 512) + row * 512 + col];
    } else {                           // out layer: row-major, padded 16x512
      const int r = (i - N2) >> 9, c = (i - N2) & 511;
      v = (r < 3) ? Wo[r * 512 + c] : 0.0f;
    }
    o[i] = (_Float16)v;
  } else if (i < N3 + NBIAS) {
    int j = i - N3;
    biasC[j] = (j < 512 ? bf[j] : bh[j - 512]) * C_SC;
  }
}

// h LDS layout: elem addr = (chunk*128 + token)*8 + (f&7), chunk = f>>3.
// b-frag ds_read_b128 addr16B = chunk*128 + token: lane-linear.
__device__ __forceinline__ int h_elem(int chunk, int token) {
  return (chunk * 128 + token) * 8;
}

// One sine layer: h <- sin(30*(W h + b)). M=512, N=128 tokens.
// Wave = 4 mt-tiles (128 feats, rows f0..f0+127) x 2 nt-tiles (64 tokens,
// tb0..tb0+63). 32x32x16 MFMA; W fragment-ordered (see convert_weights).
template <int K>
__device__ __forceinline__ void sine_layer(const _Float16* __restrict__ W,
                                           const float* __restrict__ biasC,
                                           _Float16* hb, int lane, int tk,
                                           int kg, int f0, int tb0) {
  constexpr int KS = K / 16;
  f32x16 acc[4][2];
#pragma unroll
  for (int mt = 0; mt < 4; ++mt)
#pragma unroll
    for (int nt = 0; nt < 2; ++nt)
#pragma unroll
      for (int r = 0; r < 16; ++r) acc[mt][nt][r] = 0.f;

  // per-mt fragment-ordered base: one contiguous 1KB burst per (mt, ks)
  const _Float16* wb[4];
#pragma unroll
  for (int mt = 0; mt < 4; ++mt)
    wb[mt] = &W[(((f0 >> 5) + mt) * KS) * 512 + lane * 8];

  f16x8 a[3][4], b[2][2];
#pragma unroll
  for (int mt = 0; mt < 4; ++mt) a[0][mt] = *(const f16x8*)(wb[mt]);
#pragma unroll
  for (int mt = 0; mt < 4; ++mt) a[1][mt] = *(const f16x8*)(wb[mt] + 512);
#pragma unroll
  for (int nt = 0; nt < 2; ++nt)
    b[0][nt] = *(const f16x8*)&hb[h_elem(kg, tb0 + nt * 32 + tk)];

#pragma unroll
  for (int ks = 0; ks < KS; ++ks) {
    const int cur = ks & 1;
    const int ai = ks % 3;
    if (ks + 1 < KS) {  // prefetch next k-step's b-frags under these MFMAs
#pragma unroll
      for (int nt = 0; nt < 2; ++nt)
        b[cur ^ 1][nt] =
            *(const f16x8*)&hb[h_elem((ks + 1) * 2 + kg, tb0 + nt * 32 + tk)];
    }
    if (ks + 2 < KS) {  // 2-deep a-prefetch (~590cyc cover >> 225 L2 hit)
#pragma unroll
      for (int mt = 0; mt < 4; ++mt)
        a[(ks + 2) % 3][mt] = *(const f16x8*)(wb[mt] + (ks + 2) * 512);
    }
#pragma unroll
    for (int mt = 0; mt < 4; ++mt)
#pragma unroll
      for (int nt = 0; nt < 2; ++nt)
        acc[mt][nt] = __builtin_amdgcn_mfma_f32_32x32x16_f16(
            a[ai][mt], b[cur][nt], acc[mt][nt], 0, 0, 0);
  }
  __syncthreads();  // all reads of hb done before overwrite

  // Epilogue: C/D layout col=lane&31 (token), row=(r&3)+8*(r>>2)+4*kg.
  // reg quad q=r>>2 -> 4 consecutive feats at f0+mt*32+4*kg+8*q.
#pragma unroll
  for (int mt = 0; mt < 4; ++mt) {
    const int cbase = (f0 >> 3) + mt * 4;  // h chunk base for this tile
    f32x4 bq[4];
#pragma unroll
    for (int q = 0; q < 4; ++q)
      bq[q] = *(const f32x4*)&biasC[f0 + mt * 32 + 4 * kg + 8 * q];
#pragma unroll
    for (int nt = 0; nt < 2; ++nt) {
      const int tok = tb0 + nt * 32 + tk;
#pragma unroll
      for (int q = 0; q < 4; ++q) {
        f16x4 hv;
#pragma unroll
        for (int j = 0; j < 4; ++j) {
          float pre = fmaf(acc[mt][nt][q * 4 + j], C_SC, bq[q][j]);
          hv[j] = (_Float16)__builtin_amdgcn_sinf(__builtin_amdgcn_fractf(pre));
        }
        *(f16x4*)&hb[(cbase + q) * 1024 + tok * 8 + 4 * kg] = hv;
      }
    }
  }
  __syncthreads();
}

__global__ __launch_bounds__(THREADS, 2) void siren_kernel(
    const float* __restrict__ coords, const float* __restrict__ bff,
    const float* __restrict__ biasC, const float* __restrict__ b_out,
    const _Float16* __restrict__ wf, const _Float16* __restrict__ wh,
    const _Float16* __restrict__ wo, float* __restrict__ out) {
  extern __shared__ _Float16 hb[];  // chunk-major: [64 chunks][128 tok][8]
  const int tid = threadIdx.x;
  const int t0 = blockIdx.x * TOK;

  // ---- Fourier features: chunks q*4+cb (sin), 16+q*4+cb (cos) ----
  {
    const int t = tid & 127;   // token (wave = 64 consecutive tokens)
    const int q = tid >> 7;    // feature octant: proj j in [q*32, q*32+32)
    const float c0 = coords[(t0 + t) * 3 + 0];
    const float c1 = coords[(t0 + t) * 3 + 1];
    const float c2 = coords[(t0 + t) * 3 + 2];
#pragma unroll
    for (int cb = 0; cb < 4; ++cb) {
      f16x8 sv, cv;
#pragma unroll
      for (int e = 0; e < 8; ++e) {
        const int j = q * 32 + cb * 8 + e;
        float r = fmaf(c0, bff[j], fmaf(c1, bff[128 + j], c2 * bff[256 + j]));
        float fr = __builtin_amdgcn_fractf(r);
        sv[e] = (_Float16)__builtin_amdgcn_sinf(fr);
        cv[e] = (_Float16)__builtin_amdgcn_cosf(fr);
      }
      *(f16x8*)&hb[h_elem(q * 4 + cb, t)] = sv;        // lane-linear store
      *(f16x8*)&hb[h_elem(16 + q * 4 + cb, t)] = cv;
    }
  }
  __syncthreads();

  const int lane = tid & 63;
  const int tk = lane & 31;   // 32x32: A row / B token / C token col
  const int kg = lane >> 5;   // k-group (2 halves of K=16)
  const int wave = tid >> 6;
  const int f0 = (wave >> 1) * 128;  // wave's 128-feature output slice
  const int tb0 = (wave & 1) * 64;   // wave's 64-token slice

  sine_layer<256>(wf, biasC, hb, lane, tk, kg, f0, tb0);
#pragma unroll 1
  for (int l = 0; l < 5; ++l)
    sine_layer<512>(wh + l * (512 * 512), biasC + 512 + l * 512, hb, lane, tk,
                    kg, f0, tb0);

  // ---- final linear (16x16x32): out[t][0..2], 16 tokens/wave, 8 waves ----
  {
    const int lr = lane & 15;
    const int lg = lane >> 4;
    f32x4 acc = {0.f, 0.f, 0.f, 0.f};
#pragma unroll
    for (int ks = 0; ks < 16; ++ks) {
      f16x8 a = *(const f16x8*)&wo[lr * 512 + ks * 32 + lg * 8];
      f16x8 b = *(const f16x8*)&hb[h_elem(ks * 4 + lg, wave * 16 + lr)];
      acc = __builtin_amdgcn_mfma_f32_16x16x32_f16(a, b, acc, 0, 0, 0);
    }
    if (lg == 0) {  // C rows 0..3 in lanes 0..15; out-feature = reg idx
      const int t = t0 + wave * 16 + lr;
      out[t * 3 + 0] = acc[0] + b_out[0];
      out[t * 3 + 1] = acc[1] + b_out[1];
      out[t * 3 + 2] = acc[2] + b_out[2];
    }
  }
}

extern "C" void kernel_launch(void* const* d_in, const int* in_sizes, int n_in,
                              void* d_out, int out_size, void* d_ws,
                              size_t ws_size, hipStream_t stream) {
  const float* coords = (const float*)d_in[0];
  const float* bff    = (const float*)d_in[1];
  const float* Wf     = (const float*)d_in[2];
  const float* bf     = (const float*)d_in[3];
  const float* Wh     = (const float*)d_in[4];
  const float* bh     = (const float*)d_in[5];
  const float* Wo     = (const float*)d_in[6];
  const float* bo     = (const float*)d_in[7];
  float* out = (float*)d_out;

  _Float16* w16 = (_Float16*)d_ws;
  float* biasC = (float*)(w16 + N3);  // 16B-aligned (N3*2 % 16 == 0)

  convert_weights<<<(N3 + NBIAS + 255) / 256, 256, 0, stream>>>(
      Wf, Wh, Wo, bf, bh, w16, biasC);

  const size_t lds_bytes = 64 * 128 * 8 * sizeof(_Float16);  // 131072
  siren_kernel<<<L_TOTAL / TOK, THREADS, lds_bytes, stream>>>(
      coords, bff, biasC, bo, w16, w16 + N1, w16 + N2, out);
}

// Round 4
// 753.146 us; speedup vs baseline: 1.1734x; 1.1734x over previous
//
#include <hip/hip_runtime.h>

// Fused SIREN INR round 10. Revert to r6 (739us, best known: TOK=128,
// 512 thr, 16x16x32 MFMA, fragment-ordered weights, chunk-major LDS,
// 2 barriers/layer, rolling a[3], b double-buffer) + two reg-free edits:
//  (1) drop v_fract before v_sin/v_cos: hw sin valid+reduced for
//      |x|<=256 rev; our args bounded |pre|<=9.1, FF |r|<=~114.
//  (2) persistent s_setprio(1) on waves 0-3: break 2-wave/SIMD lockstep
//      so mem-issue windows interleave under the MFMA pipe.
// LEDGER (locked):
//  - 1x weight L2 traffic mandatory. Per-CU L2 link ~56 B/cyc; r9's MT=4
//    (2x traffic, 55 B/cyc demand) stretched k-steps to the BW wall
//    (745->918us). Also kills TOK=64/2-block (64 B/cyc) and TOK=160
//    (regs). r7 token-split: same wall (+6%).
//  - LDS b-read traffic invariant (512KB/layer/CU) for 1x-weight 8-wave
//    tilings; r6==r8 perf confirms LDS is not the lever.
//  - Registers: acc 128 (AGPR) + ~128 VGPR = 256 = 2-wave cap. No
//    headroom for deeper buffers or dual-live acc (epi/K overlap).
//  - r8 (32x32x16): neutral (745). K-loop pipe util ~66% in both; gap is
//    structural (2-phase barrier schedule), not issue-pattern.

#define L_TOTAL 262144
#define TOK 128
#define THREADS 512
#define C_SC 4.77464829275686f  // 30/(2*pi)

typedef _Float16 f16x8 __attribute__((ext_vector_type(8)));
typedef _Float16 f16x4 __attribute__((ext_vector_type(4)));
typedef float    f32x4 __attribute__((ext_vector_type(4)));

#define N1 (512 * 256)                 // W_first elems
#define N2 (N1 + 5 * 512 * 512)        // + W_hidden
#define N3 (N2 + 16 * 512)             // + W_out padded to 16 rows
#define NBIAS 3072                     // 512 first + 5*512 hidden (pre-scaled)

// Fragment-ordered destination for first+hidden weights:
// dst[((mt*KS + ks)*64 + lane)*8 + e] = W[row=mt*16+(lane&15)]
//                                        [col=ks*32+(lane>>4)*8+e]
__global__ void convert_weights(const float* __restrict__ Wf,
                                const float* __restrict__ Wh,
                                const float* __restrict__ Wo,
                                const float* __restrict__ bf,
                                const float* __restrict__ bh,
                                _Float16* __restrict__ o,
                                float* __restrict__ biasC) {
  int i = blockIdx.x * blockDim.x + threadIdx.x;
  if (i < N3) {
    float v;
    if (i < N1) {                      // first layer: 512x256, KS=8
      const int blk = i >> 9, w = i & 511;
      const int lane = w >> 3, e = w & 7;
      const int mt = blk >> 3, ks = blk & 7;
      const int row = mt * 16 + (lane & 15);
      const int col = ks * 32 + (lane >> 4) * 8 + e;
      v = Wf[row * 256 + col];
    } else if (i < N2) {               // hidden: 5 x 512x512, KS=16
      int j = i - N1;
      const int l = j >> 18;
      j &= (1 << 18) - 1;
      const int blk = j >> 9, w = j & 511;
      const int lane = w >> 3, e = w & 7;
      const int mt = blk >> 4, ks = blk & 15;
      const int row = mt * 16 + (lane & 15);
      const int col = ks * 32 + (lane >> 4) * 8 + e;
      v = Wh[l * (512 * 512) + row * 512 + col];
    } else {                           // out layer: row-major, padded 16x512
      const int r = (i - N2) >> 9, c = (i - N2) & 511;
      v = (r < 3) ? Wo[r * 512 + c] : 0.0f;
    }
    o[i] = (_Float16)v;
  } else if (i < N3 + NBIAS) {
    int j = i - N3;
    biasC[j] = (j < 512 ? bf[j] : bh[j - 512]) * C_SC;
  }
}

// h LDS layout: elem addr = (chunk*128 + token)*8 + (f&7), chunk = f>>3.
// b-frag ds_read_b128 addr16B = chunk*128 + token: linear in lane ->
// conflict-free.
__device__ __forceinline__ int h_elem(int chunk, int token) {
  return (chunk * 128 + token) * 8;
}

// One sine layer: h <- sin(30*(W h + b)). M=512 (8 waves x 64 feats),
// N=128 tokens (8 ntiles), K templated (256 first / 512 hidden).
// W is fragment-ordered (see convert_weights).
template <int K>
__device__ __forceinline__ void sine_layer(const _Float16* __restrict__ W,
                                           const float* __restrict__ biasC,
                                           _Float16* hb, int lane, int lr,
                                           int lg, int m0) {
  constexpr int KS = K / 32;
  f32x4 acc[4][8];
#pragma unroll
  for (int mt = 0; mt < 4; ++mt)
#pragma unroll
    for (int nt = 0; nt < 8; ++nt)
      acc[mt][nt] = (f32x4){0.f, 0.f, 0.f, 0.f};

  // per-mt fragment-ordered base: one contiguous 1KB burst per (mt, ks)
  const _Float16* wb[4];
#pragma unroll
  for (int mt = 0; mt < 4; ++mt)
    wb[mt] = &W[(((m0 >> 4) + mt) * KS) * 512 + lane * 8];

  f16x8 a[3][4], b[2][8];
#pragma unroll
  for (int mt = 0; mt < 4; ++mt) a[0][mt] = *(const f16x8*)(wb[mt]);
#pragma unroll
  for (int mt = 0; mt < 4; ++mt) a[1][mt] = *(const f16x8*)(wb[mt] + 512);
#pragma unroll
  for (int nt = 0; nt < 8; ++nt)
    b[0][nt] = *(const f16x8*)&hb[h_elem(lg, nt * 16 + lr)];

#pragma unroll
  for (int ks = 0; ks < KS; ++ks) {
    const int cur = ks & 1;
    const int ai = ks % 3;
    if (ks + 1 < KS) {  // prefetch next k-step's b-frags under these MFMAs
#pragma unroll
      for (int nt = 0; nt < 8; ++nt)
        b[cur ^ 1][nt] =
            *(const f16x8*)&hb[h_elem((ks + 1) * 4 + lg, nt * 16 + lr)];
    }
    if (ks + 2 < KS) {  // 2-deep a-prefetch (~320cyc cover)
#pragma unroll
      for (int mt = 0; mt < 4; ++mt)
        a[(ks + 2) % 3][mt] = *(const f16x8*)(wb[mt] + (ks + 2) * 512);
    }
#pragma unroll
    for (int mt = 0; mt < 4; ++mt)
#pragma unroll
      for (int nt = 0; nt < 8; ++nt)
        acc[mt][nt] = __builtin_amdgcn_mfma_f32_16x16x32_f16(
            a[ai][mt], b[cur][nt], acc[mt][nt], 0, 0, 0);
  }
  __syncthreads();  // all reads of hb done before overwrite

#pragma unroll
  for (int mt = 0; mt < 4; ++mt) {
    const int ob = m0 + mt * 16 + lg * 4;  // 4 consecutive out-features
    const f32x4 bb = *(const f32x4*)&biasC[ob];
    const int wbase = (ob >> 3) * 128 * 8 + (ob & 7);
#pragma unroll
    for (int nt = 0; nt < 8; ++nt) {
      f16x4 hv;
#pragma unroll
      for (int r = 0; r < 4; ++r) {
        // pre in revolutions, |pre| <= ~9.1 << 256: hw v_sin reduces
        // internally (no fract needed; shortens the serial dep chain)
        float pre = fmaf(acc[mt][nt][r], C_SC, bb[r]);
        hv[r] = (_Float16)__builtin_amdgcn_sinf(pre);
      }
      *(f16x4*)&hb[wbase + (nt * 16 + lr) * 8] = hv;
    }
  }
  __syncthreads();
}

__global__ __launch_bounds__(THREADS, 2) void siren_kernel(
    const float* __restrict__ coords, const float* __restrict__ bff,
    const float* __restrict__ biasC, const float* __restrict__ b_out,
    const _Float16* __restrict__ wf, const _Float16* __restrict__ wh,
    const _Float16* __restrict__ wo, float* __restrict__ out) {
  extern __shared__ _Float16 hb[];  // chunk-major: [64 chunks][128 tok][8]
  const int tid = threadIdx.x;
  const int t0 = blockIdx.x * TOK;

  // Break 2-wave/SIMD lockstep: half the waves get elevated priority so
  // paired waves drift and their mem-issue windows interleave with MFMA.
  if ((tid >> 6) < 4) __builtin_amdgcn_s_setprio(1);

  // ---- Fourier features: chunks q*4+cb (sin), 16+q*4+cb (cos) ----
  {
    const int t = tid & 127;   // token (wave = 64 consecutive tokens)
    const int q = tid >> 7;    // feature octant: proj j in [q*32, q*32+32)
    const float c0 = coords[(t0 + t) * 3 + 0];
    const float c1 = coords[(t0 + t) * 3 + 1];
    const float c2 = coords[(t0 + t) * 3 + 2];
#pragma unroll
    for (int cb = 0; cb < 4; ++cb) {
      f16x8 sv, cv;
#pragma unroll
      for (int e = 0; e < 8; ++e) {
        const int j = q * 32 + cb * 8 + e;
        // r in revolutions, |r| <= 3*max|B_ff| ~ 114 << 256: no fract
        float r = fmaf(c0, bff[j], fmaf(c1, bff[128 + j], c2 * bff[256 + j]));
        sv[e] = (_Float16)__builtin_amdgcn_sinf(r);
        cv[e] = (_Float16)__builtin_amdgcn_cosf(r);
      }
      *(f16x8*)&hb[h_elem(q * 4 + cb, t)] = sv;        // lane-linear store
      *(f16x8*)&hb[h_elem(16 + q * 4 + cb, t)] = cv;
    }
  }
  __syncthreads();

  const int lane = tid & 63;
  const int lr = lane & 15;   // A: weight row / B: token / C: token col
  const int lg = lane >> 4;   // k-group for frags, row-group for C
  const int m0 = (tid >> 6) * 64;  // wave's 64-feature output slice

  sine_layer<256>(wf, biasC, hb, lane, lr, lg, m0);
#pragma unroll 1
  for (int l = 0; l < 5; ++l)
    sine_layer<512>(wh + l * (512 * 512), biasC + 512 + l * 512, hb, lane, lr,
                    lg, m0);

  // ---- final linear: out[t][0..2], 16 tokens per wave, 8 waves ----
  {
    const int wave = tid >> 6;
    f32x4 acc = {0.f, 0.f, 0.f, 0.f};
#pragma unroll
    for (int ks = 0; ks < 16; ++ks) {
      f16x8 a = *(const f16x8*)&wo[lr * 512 + ks * 32 + lg * 8];
      f16x8 b = *(const f16x8*)&hb[h_elem(ks * 4 + lg, wave * 16 + lr)];
      acc = __builtin_amdgcn_mfma_f32_16x16x32_f16(a, b, acc, 0, 0, 0);
    }
    if (lg == 0) {  // C rows 0..3 in lanes 0..15; out-feature = reg idx
      const int t = t0 + wave * 16 + lr;
      out[t * 3 + 0] = acc[0] + b_out[0];
      out[t * 3 + 1] = acc[1] + b_out[1];
      out[t * 3 + 2] = acc[2] + b_out[2];
    }
  }
}

extern "C" void kernel_launch(void* const* d_in, const int* in_sizes, int n_in,
                              void* d_out, int out_size, void* d_ws,
                              size_t ws_size, hipStream_t stream) {
  const float* coords = (const float*)d_in[0];
  const float* bff    = (const float*)d_in[1];
  const float* Wf     = (const float*)d_in[2];
  const float* bf     = (const float*)d_in[3];
  const float* Wh     = (const float*)d_in[4];
  const float* bh     = (const float*)d_in[5];
  const float* Wo     = (const float*)d_in[6];
  const float* bo     = (const float*)d_in[7];
  float* out = (float*)d_out;

  _Float16* w16 = (_Float16*)d_ws;
  float* biasC = (float*)(w16 + N3);  // 16B-aligned (N3*2 % 16 == 0)

  convert_weights<<<(N3 + NBIAS + 255) / 256, 256, 0, stream>>>(
      Wf, Wh, Wo, bf, bh, w16, biasC);

  const size_t lds_bytes = 64 * 128 * 8 * sizeof(_Float16);  // 131072
  siren_kernel<<<L_TOTAL / TOK, THREADS, lds_bytes, stream>>>(
      coords, bff, biasC, bo, w16, w16 + N1, w16 + N2, out);
}

// Round 5
// 740.588 us; speedup vs baseline: 1.1933x; 1.0170x over previous
//
#include <hip/hip_runtime.h>

// Fused SIREN INR round 11. r10 base (724us best: TOK=128, 512 thr,
// 16x16x32 MFMA, fragment-ordered weights, chunk-major LDS, rolling a[3],
// b double-buffer, no-fract hw sine) + FLAG-GATED LAYER PIPELINE:
// drop the post-epilogue barrier (was 2/layer -> 1/layer). K-loop of
// epoch e reads h chunk-group of k-step ks, produced solely by wave
// (ks>>1)'s epilogue of epoch e-1 -> gate each b-prefetch on
// eflag[ks>>1] >= e-1 (monotonic epoch flags in static LDS). WAR (h
// overwrite) still covered by the one barrier at K-loop end. The 2
// waves/SIMD contend during simultaneous epilogues; first finisher
// enters next K-loop (MFMA) while the other sines at full VALU rate ->
// anti-phase emerges without extra regs or weight traffic.
// Dropped persistent setprio (a spinning high-prio wave would starve its
// low-prio producer on the same SIMD).
// LEDGER (locked):
//  - 1x weight L2 traffic mandatory (r9 MT=4 2x -> 918us; r7 token-split
//    -> 787us). Kills TOK=64/2-block, TOK=160, any wave-dup geometry.
//  - Registers: acc 128 + ~128 VGPR = 256 = 2-wave cap. No dual-live acc
//    (kills deferred-epilogue interleave), no deeper buffers.
//  - LDS b-read traffic invariant across 1x-weight 8-wave tilings
//    (r6==r8 perf). 32x32x16 MFMA neutral (r8).
//  - fract-drop before v_sin/v_cos: -23us VALU, verified safe (r10).
//  - MFMA pipe floor (f16 16x16): ~357us busy. VALU ~200us. idle ~167us.

#define L_TOTAL 262144
#define TOK 128
#define THREADS 512
#define C_SC 4.77464829275686f  // 30/(2*pi)

typedef _Float16 f16x8 __attribute__((ext_vector_type(8)));
typedef _Float16 f16x4 __attribute__((ext_vector_type(4)));
typedef float    f32x4 __attribute__((ext_vector_type(4)));

#define N1 (512 * 256)                 // W_first elems
#define N2 (N1 + 5 * 512 * 512)        // + W_hidden
#define N3 (N2 + 16 * 512)             // + W_out padded to 16 rows
#define NBIAS 3072                     // 512 first + 5*512 hidden (pre-scaled)

// Fragment-ordered destination for first+hidden weights:
// dst[((mt*KS + ks)*64 + lane)*8 + e] = W[row=mt*16+(lane&15)]
//                                        [col=ks*32+(lane>>4)*8+e]
__global__ void convert_weights(const float* __restrict__ Wf,
                                const float* __restrict__ Wh,
                                const float* __restrict__ Wo,
                                const float* __restrict__ bf,
                                const float* __restrict__ bh,
                                _Float16* __restrict__ o,
                                float* __restrict__ biasC) {
  int i = blockIdx.x * blockDim.x + threadIdx.x;
  if (i < N3) {
    float v;
    if (i < N1) {                      // first layer: 512x256, KS=8
      const int blk = i >> 9, w = i & 511;
      const int lane = w >> 3, e = w & 7;
      const int mt = blk >> 3, ks = blk & 7;
      const int row = mt * 16 + (lane & 15);
      const int col = ks * 32 + (lane >> 4) * 8 + e;
      v = Wf[row * 256 + col];
    } else if (i < N2) {               // hidden: 5 x 512x512, KS=16
      int j = i - N1;
      const int l = j >> 18;
      j &= (1 << 18) - 1;
      const int blk = j >> 9, w = j & 511;
      const int lane = w >> 3, e = w & 7;
      const int mt = blk >> 4, ks = blk & 15;
      const int row = mt * 16 + (lane & 15);
      const int col = ks * 32 + (lane >> 4) * 8 + e;
      v = Wh[l * (512 * 512) + row * 512 + col];
    } else {                           // out layer: row-major, padded 16x512
      const int r = (i - N2) >> 9, c = (i - N2) & 511;
      v = (r < 3) ? Wo[r * 512 + c] : 0.0f;
    }
    o[i] = (_Float16)v;
  } else if (i < N3 + NBIAS) {
    int j = i - N3;
    biasC[j] = (j < 512 ? bf[j] : bh[j - 512]) * C_SC;
  }
}

// h LDS layout: elem addr = (chunk*128 + token)*8 + (f&7), chunk = f>>3.
// b-frag ds_read_b128 addr16B = chunk*128 + token: linear in lane ->
// conflict-free.
__device__ __forceinline__ int h_elem(int chunk, int token) {
  return (chunk * 128 + token) * 8;
}

// One sine layer: h <- sin(30*(W h + b)). M=512 (8 waves x 64 feats),
// N=128 tokens (8 ntiles), K templated (256 first / 512 hidden).
// W is fragment-ordered. Chunk-group of k-step ks (chunks 4ks..4ks+3) is
// produced by wave ks>>1's epilogue -> flag-gated prefetch (epoch > 1).
template <int K>
__device__ __forceinline__ void sine_layer(const _Float16* __restrict__ W,
                                           const float* __restrict__ biasC,
                                           _Float16* hb, volatile int* eflag,
                                           int epoch, int wave, int lane,
                                           int lr, int lg, int m0) {
  constexpr int KS = K / 32;
  f32x4 acc[4][8];
#pragma unroll
  for (int mt = 0; mt < 4; ++mt)
#pragma unroll
    for (int nt = 0; nt < 8; ++nt)
      acc[mt][nt] = (f32x4){0.f, 0.f, 0.f, 0.f};

  // per-mt fragment-ordered base: one contiguous 1KB burst per (mt, ks)
  const _Float16* wb[4];
#pragma unroll
  for (int mt = 0; mt < 4; ++mt)
    wb[mt] = &W[(((m0 >> 4) + mt) * KS) * 512 + lane * 8];

  f16x8 a[3][4], b[2][8];
  // a-loads are independent of h: issue before any flag spin
#pragma unroll
  for (int mt = 0; mt < 4; ++mt) a[0][mt] = *(const f16x8*)(wb[mt]);
#pragma unroll
  for (int mt = 0; mt < 4; ++mt) a[1][mt] = *(const f16x8*)(wb[mt] + 512);

  if (epoch > 1 && wave != 0) {  // chunks 0..3 (and 4..7) produced by wave 0
    while (eflag[0] < epoch - 1) {}
  }
#pragma unroll
  for (int nt = 0; nt < 8; ++nt)
    b[0][nt] = *(const f16x8*)&hb[h_elem(lg, nt * 16 + lr)];

#pragma unroll
  for (int ks = 0; ks < KS; ++ks) {
    const int cur = ks & 1;
    const int ai = ks % 3;
    if (ks + 1 < KS) {  // prefetch next k-step's b-frags under these MFMAs
      const int p = (ks + 1) >> 1;  // producer wave of chunks 4(ks+1)..+3
      if (epoch > 1 && p != wave && p != 0) {
        while (eflag[p] < epoch - 1) {}
      }
#pragma unroll
      for (int nt = 0; nt < 8; ++nt)
        b[cur ^ 1][nt] =
            *(const f16x8*)&hb[h_elem((ks + 1) * 4 + lg, nt * 16 + lr)];
    }
    if (ks + 2 < KS) {  // 2-deep a-prefetch (~320cyc cover)
#pragma unroll
      for (int mt = 0; mt < 4; ++mt)
        a[(ks + 2) % 3][mt] = *(const f16x8*)(wb[mt] + (ks + 2) * 512);
    }
#pragma unroll
    for (int mt = 0; mt < 4; ++mt)
#pragma unroll
      for (int nt = 0; nt < 8; ++nt)
        acc[mt][nt] = __builtin_amdgcn_mfma_f32_16x16x32_f16(
            a[ai][mt], b[cur][nt], acc[mt][nt], 0, 0, 0);
  }
  __syncthreads();  // WAR: all waves' reads of old h done before overwrite

#pragma unroll
  for (int mt = 0; mt < 4; ++mt) {
    const int ob = m0 + mt * 16 + lg * 4;  // 4 consecutive out-features
    const f32x4 bb = *(const f32x4*)&biasC[ob];
    const int wbase = (ob >> 3) * 128 * 8 + (ob & 7);
#pragma unroll
    for (int nt = 0; nt < 8; ++nt) {
      f16x4 hv;
#pragma unroll
      for (int r = 0; r < 4; ++r) {
        // pre in revolutions, |pre| <= ~9.1 << 256: hw v_sin reduces
        float pre = fmaf(acc[mt][nt][r], C_SC, bb[r]);
        hv[r] = (_Float16)__builtin_amdgcn_sinf(pre);
      }
      *(f16x4*)&hb[wbase + (nt * 16 + lr) * 8] = hv;
    }
  }
  // publish: all our chunk writes complete, then raise our epoch flag
  asm volatile("s_waitcnt lgkmcnt(0)" ::: "memory");
  if (lane == 0) eflag[wave] = epoch;
  // NO trailing barrier: consumers gate on eflag per k-step.
}

__global__ __launch_bounds__(THREADS, 2) void siren_kernel(
    const float* __restrict__ coords, const float* __restrict__ bff,
    const float* __restrict__ biasC, const float* __restrict__ b_out,
    const _Float16* __restrict__ wf, const _Float16* __restrict__ wh,
    const _Float16* __restrict__ wo, float* __restrict__ out) {
  extern __shared__ _Float16 hb[];  // chunk-major: [64 chunks][128 tok][8]
  __shared__ int eflag[8];          // per-wave epilogue epoch (monotonic)
  const int tid = threadIdx.x;
  const int t0 = blockIdx.x * TOK;

  if (tid < 8) eflag[tid] = 0;

  // ---- Fourier features: chunks q*4+cb (sin), 16+q*4+cb (cos) ----
  {
    const int t = tid & 127;   // token (wave = 64 consecutive tokens)
    const int q = tid >> 7;    // feature octant: proj j in [q*32, q*32+32)
    const float c0 = coords[(t0 + t) * 3 + 0];
    const float c1 = coords[(t0 + t) * 3 + 1];
    const float c2 = coords[(t0 + t) * 3 + 2];
#pragma unroll
    for (int cb = 0; cb < 4; ++cb) {
      f16x8 sv, cv;
#pragma unroll
      for (int e = 0; e < 8; ++e) {
        const int j = q * 32 + cb * 8 + e;
        // r in revolutions, |r| <= 3*max|B_ff| ~ 114 << 256: no fract
        float r = fmaf(c0, bff[j], fmaf(c1, bff[128 + j], c2 * bff[256 + j]));
        sv[e] = (_Float16)__builtin_amdgcn_sinf(r);
        cv[e] = (_Float16)__builtin_amdgcn_cosf(r);
      }
      *(f16x8*)&hb[h_elem(q * 4 + cb, t)] = sv;        // lane-linear store
      *(f16x8*)&hb[h_elem(16 + q * 4 + cb, t)] = cv;
    }
  }
  __syncthreads();  // h_0 ready (also covers eflag zeroing)

  const int lane = tid & 63;
  const int lr = lane & 15;   // A: weight row / B: token / C: token col
  const int lg = lane >> 4;   // k-group for frags, row-group for C
  const int wave = tid >> 6;
  const int m0 = wave * 64;   // wave's 64-feature output slice

  sine_layer<256>(wf, biasC, hb, eflag, 1, wave, lane, lr, lg, m0);
#pragma unroll 1
  for (int l = 0; l < 5; ++l)
    sine_layer<512>(wh + l * (512 * 512), biasC + 512 + l * 512, hb, eflag,
                    l + 2, wave, lane, lr, lg, m0);

  __syncthreads();  // h_6 fully published before final linear reads

  // ---- final linear: out[t][0..2], 16 tokens per wave, 8 waves ----
  {
    f32x4 acc = {0.f, 0.f, 0.f, 0.f};
#pragma unroll
    for (int ks = 0; ks < 16; ++ks) {
      f16x8 a = *(const f16x8*)&wo[lr * 512 + ks * 32 + lg * 8];
      f16x8 b = *(const f16x8*)&hb[h_elem(ks * 4 + lg, wave * 16 + lr)];
      acc = __builtin_amdgcn_mfma_f32_16x16x32_f16(a, b, acc, 0, 0, 0);
    }
    if (lg == 0) {  // C rows 0..3 in lanes 0..15; out-feature = reg idx
      const int t = t0 + wave * 16 + lr;
      out[t * 3 + 0] = acc[0] + b_out[0];
      out[t * 3 + 1] = acc[1] + b_out[1];
      out[t * 3 + 2] = acc[2] + b_out[2];
    }
  }
}

extern "C" void kernel_launch(void* const* d_in, const int* in_sizes, int n_in,
                              void* d_out, int out_size, void* d_ws,
                              size_t ws_size, hipStream_t stream) {
  const float* coords = (const float*)d_in[0];
  const float* bff    = (const float*)d_in[1];
  const float* Wf     = (const float*)d_in[2];
  const float* bf     = (const float*)d_in[3];
  const float* Wh     = (const float*)d_in[4];
  const float* bh     = (const float*)d_in[5];
  const float* Wo     = (const float*)d_in[6];
  const float* bo     = (const float*)d_in[7];
  float* out = (float*)d_out;

  _Float16* w16 = (_Float16*)d_ws;
  float* biasC = (float*)(w16 + N3);  // 16B-aligned (N3*2 % 16 == 0)

  convert_weights<<<(N3 + NBIAS + 255) / 256, 256, 0, stream>>>(
      Wf, Wh, Wo, bf, bh, w16, biasC);

  const size_t lds_bytes = 64 * 128 * 8 * sizeof(_Float16);  // 131072
  siren_kernel<<<L_TOTAL / TOK, THREADS, lds_bytes, stream>>>(
      coords, bff, biasC, bo, w16, w16 + N1, w16 + N2, out);
}